// Round 7
// baseline (168.011 us; speedup 1.0000x reference)
//
#include <hip/hip_runtime.h>
#include <math.h>
#include <stdint.h>

// ---------------------------------------------------------------------------
// EquivariantCorrectionHead, MFMA formulation v6 (precision-hardened).
// B=131072, NS=64, H=32. Block = 256 thr (4 waves), 128 batch rows/block.
// v6: GEMM1/stt use s = hi+lo bf16 split on the A side (2x MFMA, removes
// s_u rounding) and f32 (hi+lo) per-lane multiplier (removes s_v rounding).
// E/d phase moved after GEMM1 so Ed overwrites dead s regions (52KB LDS).
// o-phase identical to v5 (htp packed, i-outer gt) — spill-free at (256,2).
// ---------------------------------------------------------------------------

#define CW1 0.23904572186687872f  // sqrt(2/35)
#define CW2 0.20701966780270626f  // sqrt(3/70)
#define CW3 0.11952286093343936f  // sqrt(1/70)

typedef float f32x16 __attribute__((ext_vector_type(16)));
typedef short bf16x8 __attribute__((ext_vector_type(8)));
typedef uint32_t u32x4 __attribute__((ext_vector_type(4)));

__device__ __forceinline__ uint32_t f2bf(float f) {  // RNE float->bf16
  uint32_t x = __float_as_uint(f);
  return (x + 0x7fffu + ((x >> 16) & 1u)) >> 16;
}
__device__ __forceinline__ uint32_t packbf(float lo, float hi) {
  return f2bf(lo) | (f2bf(hi) << 16);
}
__device__ __forceinline__ float bflo(uint32_t d) { return __uint_as_float(d << 16); }
__device__ __forceinline__ float bfhi(uint32_t d) { return __uint_as_float(d & 0xffff0000u); }
__device__ __forceinline__ float bfval(uint32_t h) { return __uint_as_float(h << 16); }

__device__ __forceinline__ f32x16 zero16() {
  f32x16 z;
#pragma unroll
  for (int i = 0; i < 16; ++i) z[i] = 0.f;
  return z;
}

#define MFMA(a, b, c) __builtin_amdgcn_mfma_f32_32x32x16_bf16((a), (b), (c), 0, 0, 0)

// Pre-swizzled bf16 B-fragment tables (dword = 2 packed bf16: k, k+1).
// Fragment convention: lane l (h=l>>5, col=l&31), dword d holds k=base+8h+2d, +1.
// g_bsss is SYMMETRIZED upper-triangular: entry (u,v) = W[u,v]+W[v,u] for u<v,
// W[u,u] on diag, 0 for u>v. Plane v only needs chunks c <= v/16.
__device__ __align__(16) uint32_t g_bsss[64 * 4 * 64 * 4];  // [v][c][l][d], k=u (K=64)
__device__ __align__(16) uint32_t g_bst[5 * 4 * 64 * 4];    // [v][c][l][d], k=u (K=64)
__device__ __align__(16) uint32_t g_btts[64 * 4];           // [l][d], k=p (K=16, p15 pad)
__device__ __align__(16) uint32_t g_bttt[64 * 4];           // [l][d]
__device__ __align__(16) uint32_t g_bg2[2 * 64 * 4];        // [c][l][d], k=u (K=32)
__device__ __align__(16) uint32_t g_bgt[2 * 64 * 4];        // [c][l][d]

__device__ const int c_pu[16] = {0,0,0,0,0,1,1,1,1,2,2,2,3,3,4,0};
__device__ const int c_pv[16] = {0,1,2,3,4,1,2,3,4,2,3,4,3,4,4,0};

__global__ void ech_prep(const float* __restrict__ w1_sss, const float* __restrict__ w1_stt,
                         const float* __restrict__ w1_tst, const float* __restrict__ w1_tts,
                         const float* __restrict__ w1_ttt, const float* __restrict__ w2_stt,
                         const float* __restrict__ w2_tst, const float* __restrict__ w2_ttt) {
  const float PW1_0 = (float)(1.0 / sqrt(4121.0));
  const float PW1_2 = (float)sqrt(5.0 / 665.0);
  const float PW2_2 = (float)sqrt(5.0 / 3072.0);
  const float IS5   = (float)sqrt(0.2);

  int idx = blockIdx.x * 256 + threadIdx.x;

  if (idx < 65536) {  // g_bsss (symmetrized triangular)
    int d = idx & 3, l = (idx >> 2) & 63, c = (idx >> 8) & 3, v = idx >> 10;
    int h = l >> 5, w = l & 31;
    int u0 = c * 16 + 8 * h + 2 * d, u1 = u0 + 1;
    float lo = 0.f, hi = 0.f;
    if (u0 < v)       lo = w1_sss[(u0 * 64 + v) * 32 + w] + w1_sss[(v * 64 + u0) * 32 + w];
    else if (u0 == v) lo = w1_sss[(u0 * 64 + v) * 32 + w];
    if (u1 < v)       hi = w1_sss[(u1 * 64 + v) * 32 + w] + w1_sss[(v * 64 + u1) * 32 + w];
    else if (u1 == v) hi = w1_sss[(u1 * 64 + v) * 32 + w];
    g_bsss[idx] = packbf(PW1_0 * lo, PW1_0 * hi);
    return;
  }
  idx -= 65536;
  if (idx < 5120) {  // g_bst
    int d = idx & 3, l = (idx >> 2) & 63, c = (idx >> 8) & 3, v = idx >> 10;
    int h = l >> 5, w = l & 31;
    float sc = PW1_2 * IS5;
    int u0 = c * 16 + 8 * h + 2 * d, u1 = u0 + 1;
    g_bst[idx] = packbf(sc * (w1_stt[(u0 * 5 + v) * 32 + w] + w1_tst[(v * 64 + u0) * 32 + w]),
                        sc * (w1_stt[(u1 * 5 + v) * 32 + w] + w1_tst[(v * 64 + u1) * 32 + w]));
    return;
  }
  idx -= 5120;
  if (idx < 256) {  // g_btts
    int d = idx & 3, l = idx >> 2;
    int h = l >> 5, w = l & 31;
    float sc = PW1_0 * IS5;
    float val[2];
#pragma unroll
    for (int q = 0; q < 2; ++q) {
      int p = 8 * h + 2 * d + q;
      float x = 0.f;
      if (p < 15) {
        int u = c_pu[p], v = c_pv[p];
        x = w1_tts[(u * 5 + v) * 32 + w];
        if (u < v) x += w1_tts[(v * 5 + u) * 32 + w];
        x *= sc;
      }
      val[q] = x;
    }
    g_btts[idx] = packbf(val[0], val[1]);
    return;
  }
  idx -= 256;
  if (idx < 256) {  // g_bttt
    int d = idx & 3, l = idx >> 2;
    int h = l >> 5, w = l & 31;
    float val[2];
#pragma unroll
    for (int q = 0; q < 2; ++q) {
      int p = 8 * h + 2 * d + q;
      float x = 0.f;
      if (p < 15) {
        int u = c_pu[p], v = c_pv[p];
        x = w1_ttt[(u * 5 + v) * 32 + w];
        if (u < v) x += w1_ttt[(v * 5 + u) * 32 + w];
        x *= PW1_2;
      }
      val[q] = x;
    }
    g_bttt[idx] = packbf(val[0], val[1]);
    return;
  }
  idx -= 256;
  if (idx < 512) {  // g_bg2: B[u][v] = (w2_stt[u,v]+w2_tst[v,u])*PW2_2*IS5
    int d = idx & 3, l = (idx >> 2) & 63, c = idx >> 8;
    int h = l >> 5, v = l & 31;
    float sc = PW2_2 * IS5;
    int u0 = c * 16 + 8 * h + 2 * d, u1 = u0 + 1;
    g_bg2[idx] = packbf(sc * (w2_stt[u0 * 32 + v] + w2_tst[v * 32 + u0]),
                        sc * (w2_stt[u1 * 32 + v] + w2_tst[v * 32 + u1]));
    return;
  }
  idx -= 512;
  if (idx < 512) {  // g_bgt: B[u][v] = w2_ttt[u,v]*PW2_2
    int d = idx & 3, l = (idx >> 2) & 63, c = idx >> 8;
    int h = l >> 5, v = l & 31;
    int u0 = c * 16 + 8 * h + 2 * d, u1 = u0 + 1;
    g_bgt[idx] = packbf(PW2_2 * w2_ttt[u0 * 32 + v], PW2_2 * w2_ttt[u1 * 32 + v]);
    return;
  }
}

// LDS layout (dwords), total 13056 dw = 52224 B:
//   phase 1 (stage..stt): s_hi [128][33] @0 (4224), s_lo [128][33] @4224,
//                          t f32 [128][25] @8448 (3200, live until pack)
//   phase 2 (E/d..ttt):   Ed bf16 [128][49] @0 (6272; overwrites s_hi+s_lo)
//   phase 3 (pack..tp2):  bf16 planes [128][17]: hs @0, ht_k @2176*(k+1)
#define OFF_SLO 4224
#define OFF_T 8448
#define ED_STRIDE 49
#define LDS_DW 13056

#define ROWP(r) (((r) & 3) + 8 * ((r) >> 2) + 4 * h)

__global__ __launch_bounds__(256, 2)
void ech_fused(const float* __restrict__ scalars,
               const float* __restrict__ tk, const float* __restrict__ tm,
               const float* __restrict__ tc, const float* __restrict__ tb,
               const float* __restrict__ tmc,
               float* __restrict__ out) {
  __shared__ uint32_t lds[LDS_DW];

  const int tid = threadIdx.x;
  const int rows128 = blockIdx.x * 128;
  const int wave = tid >> 6, lane = tid & 63;
  const int h = lane >> 5, wl = lane & 31;
  const int wrow = wave * 32;

  // ---- stage s (hi + lo bf16 planes) ----
#pragma unroll
  for (int it = 0; it < 16; ++it) {
    int di = it * 256 + tid;  // 4096 dwords
    int row = di >> 5, dw = di & 31;
    float f0 = scalars[(rows128 + row) * 64 + dw * 2];
    float f1 = scalars[(rows128 + row) * 64 + dw * 2 + 1];
    uint32_t h0 = f2bf(f0), h1 = f2bf(f1);
    float r0 = f0 - bfval(h0), r1 = f1 - bfval(h1);
    lds[row * 33 + dw] = h0 | (h1 << 16);
    lds[OFF_SLO + row * 33 + dw] = f2bf(r0) | (f2bf(r1) << 16);
  }
  // ---- stage t (f32 bits as uint32) ----
#pragma unroll
  for (int v = 0; v < 5; ++v) {
    const float* p = (v == 0 ? tk : v == 1 ? tm : v == 2 ? tc : v == 3 ? tb : tmc);
#pragma unroll
    for (int it = 0; it < 3; ++it) {
      int i = it * 256 + tid;
      if (i < 640)
        lds[OFF_T + (i / 5) * 25 + v * 5 + (i % 5)] = __float_as_uint(p[rows128 * 5 + i]);
    }
  }
  __syncthreads();  // B1

  // ---- A-fragments (hi and lo) ----
  bf16x8 afr_hi[4], afr_lo[4];
#pragma unroll
  for (int c = 0; c < 4; ++c) {
    int base = (wrow + wl) * 33 + c * 8 + 4 * h;
    u32x4 t0, t1;
    t0.x = lds[base]; t0.y = lds[base + 1]; t0.z = lds[base + 2]; t0.w = lds[base + 3];
    t1.x = lds[OFF_SLO + base]; t1.y = lds[OFF_SLO + base + 1];
    t1.z = lds[OFF_SLO + base + 2]; t1.w = lds[OFF_SLO + base + 3];
    afr_hi[c] = __builtin_bit_cast(bf16x8, t0);
    afr_lo[c] = __builtin_bit_cast(bf16x8, t1);
  }

  // ---- GEMM1 (sss, triangular, hi/lo A): segment q needs chunks c<=q ----
  f32x16 hs = zero16();
  const bf16x8* gb = (const bf16x8*)g_bsss;
#pragma unroll
  for (int q = 0; q < 4; ++q) {
#pragma unroll 2
    for (int vpi = 0; vpi < 8; ++vpi) {
      int vp = q * 8 + vpi;
      f32x16 Z0 = zero16(), Z1 = zero16();
#pragma unroll
      for (int c = 0; c <= q; ++c) {
        bf16x8 b0 = gb[(2 * vp) * 256 + c * 64 + lane];
        bf16x8 b1 = gb[(2 * vp + 1) * 256 + c * 64 + lane];
        Z0 = MFMA(afr_hi[c], b0, Z0);
        Z0 = MFMA(afr_lo[c], b0, Z0);
        Z1 = MFMA(afr_hi[c], b1, Z1);
        Z1 = MFMA(afr_lo[c], b1, Z1);
      }
#pragma unroll
      for (int r = 0; r < 16; ++r) {
        int row = wrow + ROWP(r);
        uint32_t dhi = lds[row * 33 + vp];            // broadcast reads
        uint32_t dlo = lds[OFF_SLO + row * 33 + vp];
        float s0 = bflo(dhi) + bflo(dlo);             // f32 multiplier
        float s1 = bfhi(dhi) + bfhi(dlo);
        hs[r] = fmaf(s0, Z0[r], hs[r]);
        hs[r] = fmaf(s1, Z1[r], hs[r]);
      }
    }
  }

  // ---- stt GEMM (hi/lo A) folded directly into ht ----
  f32x16 ht[5];
#pragma unroll
  for (int k = 0; k < 5; ++k) ht[k] = zero16();
  {
    const bf16x8* gs = (const bf16x8*)g_bst;
#pragma unroll
    for (int ct = 0; ct < 5; ++ct) {
      f32x16 acc = zero16();
#pragma unroll
      for (int c = 0; c < 4; ++c) {
        bf16x8 b = gs[(ct * 4 + c) * 64 + lane];
        acc = MFMA(afr_hi[c], b, acc);
        acc = MFMA(afr_lo[c], b, acc);
      }
#pragma unroll
      for (int r = 0; r < 16; ++r) {
        int row = wrow + ROWP(r);
        float av = acc[r];
#pragma unroll
        for (int k = 0; k < 5; ++k)
          ht[k][r] = fmaf(av, __uint_as_float(lds[OFF_T + row * 25 + ct * 5 + k]), ht[k][r]);
      }
    }
  }
  __syncthreads();  // B2: s_hi/s_lo dead; Ed region becomes writable

  // ---- E/d phase: 2 threads per row, writes Ed @0 stride 49 ----
  {
    int row = tid >> 1, part = tid & 1;
    float t_[5][5];
#pragma unroll
    for (int v = 0; v < 5; ++v)
#pragma unroll
      for (int k = 0; k < 5; ++k) t_[v][k] = __uint_as_float(lds[OFF_T + row * 25 + v * 5 + k]);

    float PA[6], PB[6];
#define EDP(U, V, OUT)                                                            \
  {                                                                               \
    float d0_ = t_[U][0] * t_[V][0], d1_ = t_[U][1] * t_[V][1];                   \
    float d2_ = t_[U][2] * t_[V][2], d3_ = t_[U][3] * t_[V][3];                   \
    float d4_ = t_[U][4] * t_[V][4];                                              \
    float s01_ = t_[U][0] * t_[V][1] + t_[U][1] * t_[V][0];                       \
    float s02_ = t_[U][0] * t_[V][2] + t_[U][2] * t_[V][0];                       \
    float s03_ = t_[U][0] * t_[V][3] + t_[U][3] * t_[V][0];                       \
    float s12_ = t_[U][1] * t_[V][2] + t_[U][2] * t_[V][1];                       \
    float s13_ = t_[U][1] * t_[V][3] + t_[U][3] * t_[V][1];                       \
    float s14_ = t_[U][1] * t_[V][4] + t_[U][4] * t_[V][1];                       \
    float s23_ = t_[U][2] * t_[V][3] + t_[U][3] * t_[V][2];                       \
    float s24_ = t_[U][2] * t_[V][4] + t_[U][4] * t_[V][2];                       \
    float s34_ = t_[U][3] * t_[V][4] + t_[U][4] * t_[V][3];                       \
    OUT[0] = -CW1 * s02_ + CW2 * s13_;                                            \
    OUT[1] = CW2 * s03_ + CW3 * s12_ - CW2 * s14_;                                \
    OUT[2] = -CW1 * d0_ + CW3 * d1_ + CW1 * d2_ + CW3 * d3_ - CW1 * d4_;          \
    OUT[3] = CW2 * s01_ + CW3 * s23_ + CW2 * s34_;                                \
    OUT[4] = -CW2 * d1_ - CW1 * s24_ + CW2 * d3_;                                 \
    OUT[5] = d0_ + d1_ + d2_ + d3_ + d4_;                                         \
  }
#define STEDP(j)                                                                  \
  {                                                                               \
    lds[rb + 0 * 8 + (j)] = packbf(PA[0], PB[0]);                                 \
    lds[rb + 1 * 8 + (j)] = packbf(PA[1], PB[1]);                                 \
    lds[rb + 2 * 8 + (j)] = packbf(PA[2], PB[2]);                                 \
    lds[rb + 3 * 8 + (j)] = packbf(PA[3], PB[3]);                                 \
    lds[rb + 4 * 8 + (j)] = packbf(PA[4], PB[4]);                                 \
    lds[rb + 40 + (j)] = packbf(PA[5], PB[5]);                                    \
  }
    int rb = row * ED_STRIDE + (part ? 4 : 0);
    if (part == 0) {
      EDP(0, 0, PA) EDP(0, 1, PB) STEDP(0)
      EDP(0, 2, PA) EDP(0, 3, PB) STEDP(1)
      EDP(0, 4, PA) EDP(1, 1, PB) STEDP(2)
      EDP(1, 2, PA) EDP(1, 3, PB) STEDP(3)
    } else {
      EDP(1, 4, PA) EDP(2, 2, PB) STEDP(0)
      EDP(2, 3, PA) EDP(2, 4, PB) STEDP(1)
      EDP(3, 3, PA) EDP(3, 4, PB) STEDP(2)
      EDP(4, 4, PA)
#pragma unroll
      for (int q = 0; q < 6; ++q) PB[q] = 0.f;
      STEDP(3)
    }
#undef EDP
#undef STEDP
  }
  __syncthreads();  // B3

  // ---- tts GEMM into hs ----
  {
    int base = (wrow + wl) * ED_STRIDE + 40 + 4 * h;
    u32x4 tmp;
    tmp.x = lds[base]; tmp.y = lds[base + 1]; tmp.z = lds[base + 2]; tmp.w = lds[base + 3];
    hs = MFMA(__builtin_bit_cast(bf16x8, tmp), ((const bf16x8*)g_btts)[lane], hs);
  }
  // ---- ttt: per-k GEMM over pair-invariants ----
  {
    bf16x8 btt = ((const bf16x8*)g_bttt)[lane];
#pragma unroll
    for (int k = 0; k < 5; ++k) {
      int base = (wrow + wl) * ED_STRIDE + k * 8 + 4 * h;
      u32x4 tmp;
      tmp.x = lds[base]; tmp.y = lds[base + 1]; tmp.z = lds[base + 2]; tmp.w = lds[base + 3];
      ht[k] = MFMA(__builtin_bit_cast(bf16x8, tmp), btt, ht[k]);
    }
  }

  // ---- pack hs + ht planes to LDS, and ht into packed-bf16 REGISTERS ----
  __syncthreads();  // B4: Ed/t dead everywhere; plane region writable
  uint32_t htp[5][8];
  {
#pragma unroll
    for (int r = 0; r < 16; ++r) {
      int row = wrow + ROWP(r);
      float v0 = hs[r];
      float pv = __shfl_xor(v0, 1, 64);
      if (!(wl & 1)) lds[row * 17 + (wl >> 1)] = packbf(v0, pv);
#pragma unroll
      for (int k = 0; k < 5; ++k) {
        float w0 = ht[k][r];
        float pw = __shfl_xor(w0, 1, 64);
        if (!(wl & 1)) lds[2176 * (k + 1) + row * 17 + (wl >> 1)] = packbf(w0, pw);
      }
    }
#pragma unroll
    for (int k = 0; k < 5; ++k)
#pragma unroll
      for (int q = 0; q < 8; ++q)
        htp[k][q] = packbf(ht[k][2 * q], ht[k][2 * q + 1]);
  }
  __syncthreads();  // B5
  // ht (f32) registers die here; htp (40 regs) carries the values.

#define HTF(k, r) (((r) & 1) ? bfhi(htp[k][(r) >> 1]) : bflo(htp[k][(r) >> 1]))

  // ---- g2 GEMM: g2[b,v] = hs @ w2c ----
  f32x16 g2 = zero16();
#pragma unroll
  for (int c = 0; c < 2; ++c) {
    int base = (wrow + wl) * 17 + c * 8 + 4 * h;
    u32x4 tmp;
    tmp.x = lds[base]; tmp.y = lds[base + 1]; tmp.z = lds[base + 2]; tmp.w = lds[base + 3];
    g2 = MFMA(__builtin_bit_cast(bf16x8, tmp), ((const bf16x8*)g_bg2)[c * 64 + lane], g2);
  }

  // ---- o init: stt part (g2 products) ----
  f32x16 o[5];
#pragma unroll
  for (int j = 0; j < 5; ++j)
#pragma unroll
    for (int r = 0; r < 16; ++r) o[j][r] = g2[r] * HTF(j, r);

  // ---- ttt part: i-outer, single gt live at a time ----
#pragma unroll
  for (int i = 0; i < 5; ++i) {
    f32x16 gt = zero16();
#pragma unroll
    for (int c = 0; c < 2; ++c) {
      int base = 2176 * (1 + i) + (wrow + wl) * 17 + c * 8 + 4 * h;
      u32x4 tmp;
      tmp.x = lds[base]; tmp.y = lds[base + 1]; tmp.z = lds[base + 2]; tmp.w = lds[base + 3];
      gt = MFMA(__builtin_bit_cast(bf16x8, tmp), ((const bf16x8*)g_bgt)[c * 64 + lane], gt);
    }
#pragma unroll
    for (int r = 0; r < 16; ++r) {
      float p0 = gt[r] * HTF(0, r), p1 = gt[r] * HTF(1, r), p2 = gt[r] * HTF(2, r);
      float p3 = gt[r] * HTF(3, r), p4 = gt[r] * HTF(4, r);
      if (i == 0) {
        o[2][r] = fmaf(-CW1, p0, o[2][r]); o[3][r] = fmaf(CW2, p1, o[3][r]);
        o[0][r] = fmaf(-CW1, p2, o[0][r]); o[1][r] = fmaf(CW2, p3, o[1][r]);
      } else if (i == 1) {
        o[3][r] = fmaf(CW2, p0, o[3][r]);
        o[2][r] = fmaf(CW3, p1, o[2][r]); o[4][r] = fmaf(-CW2, p1, o[4][r]);
        o[1][r] = fmaf(CW3, p2, o[1][r]); o[0][r] = fmaf(CW2, p3, o[0][r]);
        o[1][r] = fmaf(-CW2, p4, o[1][r]);
      } else if (i == 2) {
        o[0][r] = fmaf(-CW1, p0, o[0][r]); o[1][r] = fmaf(CW3, p1, o[1][r]);
        o[2][r] = fmaf(CW1, p2, o[2][r]);  o[3][r] = fmaf(CW3, p3, o[3][r]);
        o[4][r] = fmaf(-CW1, p4, o[4][r]);
      } else if (i == 3) {
        o[1][r] = fmaf(CW2, p0, o[1][r]); o[0][r] = fmaf(CW2, p1, o[0][r]);
        o[3][r] = fmaf(CW3, p2, o[3][r]);
        o[2][r] = fmaf(CW3, p3, o[2][r]); o[4][r] = fmaf(CW2, p3, o[4][r]);
        o[3][r] = fmaf(CW2, p4, o[3][r]);
      } else {
        o[1][r] = fmaf(-CW2, p1, o[1][r]); o[4][r] = fmaf(-CW1, p2, o[4][r]);
        o[3][r] = fmaf(CW2, p3, o[3][r]);  o[2][r] = fmaf(-CW1, p4, o[2][r]);
      }
    }
  }

  // ---- butterfly reduce over the 32 lane-columns (v) within each half ----
#pragma unroll
  for (int m = 1; m <= 16; m <<= 1) {
#pragma unroll
    for (int k = 0; k < 5; ++k)
#pragma unroll
      for (int r = 0; r < 16; ++r) o[k][r] += __shfl_xor(o[k][r], m, 64);
  }

  // ---- direct stores: lanes with wl==k store plane k for their rows ----
#pragma unroll
  for (int k = 0; k < 5; ++k) {
    if (wl == k) {
#pragma unroll
      for (int r = 0; r < 16; ++r)
        out[(size_t)(rows128 + wrow + ROWP(r)) * 5 + k] = o[k][r];
    }
  }
}

extern "C" void kernel_launch(void* const* d_in, const int* in_sizes, int n_in,
                              void* d_out, int out_size, void* d_ws, size_t ws_size,
                              hipStream_t stream) {
  (void)n_in; (void)out_size; (void)d_ws; (void)ws_size;
  const float* scalars = (const float*)d_in[0];
  const float* tk  = (const float*)d_in[1];
  const float* tm  = (const float*)d_in[2];
  const float* tc  = (const float*)d_in[3];
  const float* tb  = (const float*)d_in[4];
  const float* tmc = (const float*)d_in[5];

  ech_prep<<<282, 256, 0, stream>>>((const float*)d_in[6], (const float*)d_in[7],
                                    (const float*)d_in[8], (const float*)d_in[9],
                                    (const float*)d_in[10], (const float*)d_in[11],
                                    (const float*)d_in[12], (const float*)d_in[13]);

  const int B = in_sizes[0] / 64;
  ech_fused<<<B / 128, 256, 0, stream>>>(scalars, tk, tm, tc, tb, tmc, (float*)d_out);
}

// Round 8
// 139.724 us; speedup vs baseline: 1.2024x; 1.2024x over previous
//
#include <hip/hip_runtime.h>
#include <math.h>
#include <stdint.h>

// ---------------------------------------------------------------------------
// EquivariantCorrectionHead, MFMA formulation v7 (16x16x32 fragments).
// B=131072, NS=64, H=32. Block = 256 thr (4 waves), 64 batch rows/block.
// Each wave owns 16 rows; all accumulators are f32x4 -> spill-free at
// launch_bounds(256,3). s hi+lo bf16 split (A side) + f32 multiplier keeps
// absmax ~0.06. Per-k o-streaming + immediate butterfly removes o[5] array.
// LDS 26KB with region reuse: s(hi/lo)+t -> Ed -> 6 bf16 planes.
// ---------------------------------------------------------------------------

#define CW1 0.23904572186687872f  // sqrt(2/35)
#define CW2 0.20701966780270626f  // sqrt(3/70)
#define CW3 0.11952286093343936f  // sqrt(1/70)

typedef float f32x4 __attribute__((ext_vector_type(4)));
typedef short bf16x8 __attribute__((ext_vector_type(8)));
typedef uint32_t u32x4 __attribute__((ext_vector_type(4)));

__device__ __forceinline__ uint32_t f2bf(float f) {  // RNE float->bf16
  uint32_t x = __float_as_uint(f);
  return (x + 0x7fffu + ((x >> 16) & 1u)) >> 16;
}
__device__ __forceinline__ uint32_t packbf(float lo, float hi) {
  return f2bf(lo) | (f2bf(hi) << 16);
}
__device__ __forceinline__ float bflo(uint32_t d) { return __uint_as_float(d << 16); }
__device__ __forceinline__ float bfhi(uint32_t d) { return __uint_as_float(d & 0xffff0000u); }
__device__ __forceinline__ float bfval(uint32_t h) { return __uint_as_float(h << 16); }

#define MF16(a, b, c) __builtin_amdgcn_mfma_f32_16x16x32_bf16((a), (b), (c), 0, 0, 0)

// B-fragment tables, 16x16x32 convention:
// lane l: g=l>>4, col=l&15 (col index = n*16 + (l&15)); dword d holds
// k = 32*c + 8*g + 2*d and k+1 (c = K-chunk where applicable).
// g_bsss16 is SYMMETRIZED upper-triangular in u (k=u): plane v needs c <= v>>5.
__device__ __align__(16) uint32_t g_bsss16[64 * 2 * 2 * 64 * 4];  // [v][n][c][l][d]
__device__ __align__(16) uint32_t g_bst16[5 * 2 * 2 * 64 * 4];    // [ct][n][c][l][d]
__device__ __align__(16) uint32_t g_btts16[2 * 64 * 4];           // [n][l][d], k=pair
__device__ __align__(16) uint32_t g_bttt16[2 * 64 * 4];           // [n][l][d], k=pair
__device__ __align__(16) uint32_t g_bg2_16[2 * 64 * 4];           // [n][l][d], k=u(32)
__device__ __align__(16) uint32_t g_bgt16[2 * 64 * 4];            // [n][l][d], k=u(32)

__device__ const int c_pu[16] = {0,0,0,0,0,1,1,1,1,2,2,2,3,3,4,0};
__device__ const int c_pv[16] = {0,1,2,3,4,1,2,3,4,2,3,4,3,4,4,0};

__global__ void ech_prep(const float* __restrict__ w1_sss, const float* __restrict__ w1_stt,
                         const float* __restrict__ w1_tst, const float* __restrict__ w1_tts,
                         const float* __restrict__ w1_ttt, const float* __restrict__ w2_stt,
                         const float* __restrict__ w2_tst, const float* __restrict__ w2_ttt) {
  const float PW1_0 = (float)(1.0 / sqrt(4121.0));
  const float PW1_2 = (float)sqrt(5.0 / 665.0);
  const float PW2_2 = (float)sqrt(5.0 / 3072.0);
  const float IS5   = (float)sqrt(0.2);

  int idx = blockIdx.x * 256 + threadIdx.x;

  if (idx < 65536) {  // g_bsss16 (symmetrized triangular)
    int d = idx & 3, l = (idx >> 2) & 63, c = (idx >> 8) & 1, n = (idx >> 9) & 1, v = idx >> 10;
    int gg = l >> 4, w = n * 16 + (l & 15);
    int u0 = 32 * c + 8 * gg + 2 * d, u1 = u0 + 1;
    float lo = 0.f, hi = 0.f;
    if (u0 < v)       lo = w1_sss[(u0 * 64 + v) * 32 + w] + w1_sss[(v * 64 + u0) * 32 + w];
    else if (u0 == v) lo = w1_sss[(u0 * 64 + v) * 32 + w];
    if (u1 < v)       hi = w1_sss[(u1 * 64 + v) * 32 + w] + w1_sss[(v * 64 + u1) * 32 + w];
    else if (u1 == v) hi = w1_sss[(u1 * 64 + v) * 32 + w];
    g_bsss16[idx] = packbf(PW1_0 * lo, PW1_0 * hi);
    return;
  }
  idx -= 65536;
  if (idx < 5120) {  // g_bst16
    int d = idx & 3, l = (idx >> 2) & 63, c = (idx >> 8) & 1, n = (idx >> 9) & 1, ct = idx >> 10;
    int gg = l >> 4, w = n * 16 + (l & 15);
    float sc = PW1_2 * IS5;
    int u0 = 32 * c + 8 * gg + 2 * d, u1 = u0 + 1;
    g_bst16[idx] = packbf(sc * (w1_stt[(u0 * 5 + ct) * 32 + w] + w1_tst[(ct * 64 + u0) * 32 + w]),
                          sc * (w1_stt[(u1 * 5 + ct) * 32 + w] + w1_tst[(ct * 64 + u1) * 32 + w]));
    return;
  }
  idx -= 5120;
  if (idx < 512) {  // g_btts16
    int d = idx & 3, l = (idx >> 2) & 63, n = idx >> 8;
    int gg = l >> 4, w = n * 16 + (l & 15);
    float sc = PW1_0 * IS5;
    float val[2];
#pragma unroll
    for (int q = 0; q < 2; ++q) {
      int p = 8 * gg + 2 * d + q;
      float x = 0.f;
      if (p < 15) {
        int u = c_pu[p], v = c_pv[p];
        x = w1_tts[(u * 5 + v) * 32 + w];
        if (u < v) x += w1_tts[(v * 5 + u) * 32 + w];
        x *= sc;
      }
      val[q] = x;
    }
    g_btts16[idx] = packbf(val[0], val[1]);
    return;
  }
  idx -= 512;
  if (idx < 512) {  // g_bttt16
    int d = idx & 3, l = (idx >> 2) & 63, n = idx >> 8;
    int gg = l >> 4, w = n * 16 + (l & 15);
    float val[2];
#pragma unroll
    for (int q = 0; q < 2; ++q) {
      int p = 8 * gg + 2 * d + q;
      float x = 0.f;
      if (p < 15) {
        int u = c_pu[p], v = c_pv[p];
        x = w1_ttt[(u * 5 + v) * 32 + w];
        if (u < v) x += w1_ttt[(v * 5 + u) * 32 + w];
        x *= PW1_2;
      }
      val[q] = x;
    }
    g_bttt16[idx] = packbf(val[0], val[1]);
    return;
  }
  idx -= 512;
  if (idx < 512) {  // g_bg2_16
    int d = idx & 3, l = (idx >> 2) & 63, n = idx >> 8;
    int gg = l >> 4, v = n * 16 + (l & 15);
    float sc = PW2_2 * IS5;
    int u0 = 8 * gg + 2 * d, u1 = u0 + 1;
    g_bg2_16[idx] = packbf(sc * (w2_stt[u0 * 32 + v] + w2_tst[v * 32 + u0]),
                           sc * (w2_stt[u1 * 32 + v] + w2_tst[v * 32 + u1]));
    return;
  }
  idx -= 512;
  if (idx < 512) {  // g_bgt16
    int d = idx & 3, l = (idx >> 2) & 63, n = idx >> 8;
    int gg = l >> 4, v = n * 16 + (l & 15);
    int u0 = 8 * gg + 2 * d, u1 = u0 + 1;
    g_bgt16[idx] = packbf(PW2_2 * w2_ttt[u0 * 32 + v], PW2_2 * w2_ttt[u1 * 32 + v]);
    return;
  }
}

// LDS (dwords), total 6528 dw = 26112 B:
//  phase1: s interleaved hi/lo [64 rows][66] @0 (4224); t f32 [64][25] @4224 (1600)
//  phase2: Ed bf16 [64 rows][49] @0 (3136; overwrites s; t stays live)
//  phase3: planes bf16 [64 rows][17] x6 @ i*1088 (6528; overwrites everything)
#define OFF_T 4224
#define ED_STRIDE 49
#define PLANE(i) ((i) * 1088)
#define LDS_DW 6528

__global__ __launch_bounds__(256, 3)
void ech_fused(const float* __restrict__ scalars,
               const float* __restrict__ tk, const float* __restrict__ tm,
               const float* __restrict__ tc, const float* __restrict__ tb,
               const float* __restrict__ tmc,
               float* __restrict__ out) {
  __shared__ uint32_t lds[LDS_DW];

  const int tid = threadIdx.x;
  const int rows64 = blockIdx.x * 64;
  const int wave = tid >> 6, lane = tid & 63;
  const int g = lane >> 4, col16 = lane & 15;
  const int wrow = wave * 16;
  const f32x4 zero4 = {0.f, 0.f, 0.f, 0.f};

  // ---- stage s: hi/lo interleaved, row stride 66 (dword 2j=hi pair, 2j+1=lo) ----
#pragma unroll
  for (int it = 0; it < 8; ++it) {
    int di = it * 256 + tid;  // 2048
    int row = di >> 5, j = di & 31;
    float f0 = scalars[(rows64 + row) * 64 + 2 * j];
    float f1 = scalars[(rows64 + row) * 64 + 2 * j + 1];
    uint32_t h0 = f2bf(f0), h1 = f2bf(f1);
    float r0 = f0 - bfval(h0), r1 = f1 - bfval(h1);
    lds[row * 66 + 2 * j]     = h0 | (h1 << 16);
    lds[row * 66 + 2 * j + 1] = f2bf(r0) | (f2bf(r1) << 16);
  }
  // ---- stage t ----
#pragma unroll
  for (int v = 0; v < 5; ++v) {
    const float* p = (v == 0 ? tk : v == 1 ? tm : v == 2 ? tc : v == 3 ? tb : tmc);
#pragma unroll
    for (int it = 0; it < 2; ++it) {
      int i = it * 256 + tid;
      if (i < 320)
        lds[OFF_T + (i / 5) * 25 + v * 5 + (i % 5)] = __float_as_uint(p[rows64 * 5 + i]);
    }
  }
  __syncthreads();  // B1

  // ---- A-fragments for s (hi, lo), K-chunks c=0,1 ----
  bf16x8 afr_hi[2], afr_lo[2];
#pragma unroll
  for (int c = 0; c < 2; ++c) {
    int base = (wrow + col16) * 66 + 32 * c + 8 * g;
    u32x4 th, tl;
    th.x = lds[base + 0]; tl.x = lds[base + 1];
    th.y = lds[base + 2]; tl.y = lds[base + 3];
    th.z = lds[base + 4]; tl.z = lds[base + 5];
    th.w = lds[base + 6]; tl.w = lds[base + 7];
    afr_hi[c] = __builtin_bit_cast(bf16x8, th);
    afr_lo[c] = __builtin_bit_cast(bf16x8, tl);
  }

  // ---- GEMM1 (sss, triangular, hi/lo A, f32 multiplier) ----
  f32x4 hsA = zero4, hsB = zero4;  // n=0, n=1
  const bf16x8* gb = (const bf16x8*)g_bsss16;
#pragma unroll 2
  for (int vd = 0; vd < 16; ++vd) {  // v<32: chunk c=0 only
    int v0 = 2 * vd, v1 = v0 + 1;
    bf16x8 b00 = gb[(v0 * 4 + 0) * 64 + lane];
    bf16x8 b01 = gb[(v0 * 4 + 2) * 64 + lane];
    bf16x8 b10 = gb[(v1 * 4 + 0) * 64 + lane];
    bf16x8 b11 = gb[(v1 * 4 + 2) * 64 + lane];
    f32x4 Z00 = zero4, Z01 = zero4, Z10 = zero4, Z11 = zero4;
    Z00 = MF16(afr_hi[0], b00, Z00); Z00 = MF16(afr_lo[0], b00, Z00);
    Z01 = MF16(afr_hi[0], b01, Z01); Z01 = MF16(afr_lo[0], b01, Z01);
    Z10 = MF16(afr_hi[0], b10, Z10); Z10 = MF16(afr_lo[0], b10, Z10);
    Z11 = MF16(afr_hi[0], b11, Z11); Z11 = MF16(afr_lo[0], b11, Z11);
#pragma unroll
    for (int r = 0; r < 4; ++r) {
      int row = wrow + 4 * g + r;
      uint32_t dh = lds[row * 66 + 2 * vd];
      uint32_t dl = lds[row * 66 + 2 * vd + 1];
      float s0 = bflo(dh) + bflo(dl);
      float s1 = bfhi(dh) + bfhi(dl);
      hsA[r] = fmaf(s0, Z00[r], hsA[r]); hsA[r] = fmaf(s1, Z10[r], hsA[r]);
      hsB[r] = fmaf(s0, Z01[r], hsB[r]); hsB[r] = fmaf(s1, Z11[r], hsB[r]);
    }
  }
#pragma unroll 2
  for (int vd = 16; vd < 32; ++vd) {  // v>=32: chunks c=0,1
    int v0 = 2 * vd, v1 = v0 + 1;
    f32x4 Z00 = zero4, Z01 = zero4, Z10 = zero4, Z11 = zero4;
#pragma unroll
    for (int c = 0; c < 2; ++c) {
      bf16x8 b00 = gb[(v0 * 4 + 0 + c) * 64 + lane];
      bf16x8 b01 = gb[(v0 * 4 + 2 + c) * 64 + lane];
      bf16x8 b10 = gb[(v1 * 4 + 0 + c) * 64 + lane];
      bf16x8 b11 = gb[(v1 * 4 + 2 + c) * 64 + lane];
      Z00 = MF16(afr_hi[c], b00, Z00); Z00 = MF16(afr_lo[c], b00, Z00);
      Z01 = MF16(afr_hi[c], b01, Z01); Z01 = MF16(afr_lo[c], b01, Z01);
      Z10 = MF16(afr_hi[c], b10, Z10); Z10 = MF16(afr_lo[c], b10, Z10);
      Z11 = MF16(afr_hi[c], b11, Z11); Z11 = MF16(afr_lo[c], b11, Z11);
    }
#pragma unroll
    for (int r = 0; r < 4; ++r) {
      int row = wrow + 4 * g + r;
      uint32_t dh = lds[row * 66 + 2 * vd];
      uint32_t dl = lds[row * 66 + 2 * vd + 1];
      float s0 = bflo(dh) + bflo(dl);
      float s1 = bfhi(dh) + bfhi(dl);
      hsA[r] = fmaf(s0, Z00[r], hsA[r]); hsA[r] = fmaf(s1, Z10[r], hsA[r]);
      hsB[r] = fmaf(s0, Z01[r], hsB[r]); hsB[r] = fmaf(s1, Z11[r], hsB[r]);
    }
  }

  // ---- stt GEMM folded into ht[k][n] ----
  f32x4 ht[5][2];
#pragma unroll
  for (int k = 0; k < 5; ++k) { ht[k][0] = zero4; ht[k][1] = zero4; }
  {
    const bf16x8* gs = (const bf16x8*)g_bst16;
#pragma unroll
    for (int ct = 0; ct < 5; ++ct) {
      f32x4 a0 = zero4, a1 = zero4;
#pragma unroll
      for (int c = 0; c < 2; ++c) {
        bf16x8 b0 = gs[(ct * 4 + 0 + c) * 64 + lane];
        bf16x8 b1 = gs[(ct * 4 + 2 + c) * 64 + lane];
        a0 = MF16(afr_hi[c], b0, a0); a0 = MF16(afr_lo[c], b0, a0);
        a1 = MF16(afr_hi[c], b1, a1); a1 = MF16(afr_lo[c], b1, a1);
      }
#pragma unroll
      for (int r = 0; r < 4; ++r) {
        int row = wrow + 4 * g + r;
        int tbi = OFF_T + row * 25 + ct * 5;
        float t0 = __uint_as_float(lds[tbi + 0]);
        float t1 = __uint_as_float(lds[tbi + 1]);
        float t2 = __uint_as_float(lds[tbi + 2]);
        float t3 = __uint_as_float(lds[tbi + 3]);
        float t4 = __uint_as_float(lds[tbi + 4]);
        ht[0][0][r] = fmaf(a0[r], t0, ht[0][0][r]); ht[0][1][r] = fmaf(a1[r], t0, ht[0][1][r]);
        ht[1][0][r] = fmaf(a0[r], t1, ht[1][0][r]); ht[1][1][r] = fmaf(a1[r], t1, ht[1][1][r]);
        ht[2][0][r] = fmaf(a0[r], t2, ht[2][0][r]); ht[2][1][r] = fmaf(a1[r], t2, ht[2][1][r]);
        ht[3][0][r] = fmaf(a0[r], t3, ht[3][0][r]); ht[3][1][r] = fmaf(a1[r], t3, ht[3][1][r]);
        ht[4][0][r] = fmaf(a0[r], t4, ht[4][0][r]); ht[4][1][r] = fmaf(a1[r], t4, ht[4][1][r]);
      }
    }
  }
  __syncthreads();  // B2: s region dead; Ed becomes writable

  // ---- E/d phase: 4 threads per row; EDP inputs read from LDS (t region) ----
  {
    int row = tid >> 2, part = tid & 3;
    int tbase = OFF_T + row * 25;
    float P[4][6];
#pragma unroll
    for (int q = 0; q < 4; ++q) {
      int p = part * 4 + q;
      int U = c_pu[p], V = c_pv[p];
      float a0 = __uint_as_float(lds[tbase + U * 5 + 0]);
      float a1 = __uint_as_float(lds[tbase + U * 5 + 1]);
      float a2 = __uint_as_float(lds[tbase + U * 5 + 2]);
      float a3 = __uint_as_float(lds[tbase + U * 5 + 3]);
      float a4 = __uint_as_float(lds[tbase + U * 5 + 4]);
      float b0 = __uint_as_float(lds[tbase + V * 5 + 0]);
      float b1 = __uint_as_float(lds[tbase + V * 5 + 1]);
      float b2 = __uint_as_float(lds[tbase + V * 5 + 2]);
      float b3 = __uint_as_float(lds[tbase + V * 5 + 3]);
      float b4 = __uint_as_float(lds[tbase + V * 5 + 4]);
      float d0 = a0 * b0, d1 = a1 * b1, d2 = a2 * b2, d3 = a3 * b3, d4 = a4 * b4;
      float s01 = a0 * b1 + a1 * b0;
      float s02 = a0 * b2 + a2 * b0;
      float s03 = a0 * b3 + a3 * b0;
      float s12 = a1 * b2 + a2 * b1;
      float s13 = a1 * b3 + a3 * b1;
      float s14 = a1 * b4 + a4 * b1;
      float s23 = a2 * b3 + a3 * b2;
      float s24 = a2 * b4 + a4 * b2;
      float s34 = a3 * b4 + a4 * b3;
      P[q][0] = -CW1 * s02 + CW2 * s13;
      P[q][1] = CW2 * s03 + CW3 * s12 - CW2 * s14;
      P[q][2] = -CW1 * d0 + CW3 * d1 + CW1 * d2 + CW3 * d3 - CW1 * d4;
      P[q][3] = CW2 * s01 + CW3 * s23 + CW2 * s34;
      P[q][4] = -CW2 * d1 - CW1 * s24 + CW2 * d3;
      P[q][5] = d0 + d1 + d2 + d3 + d4;
      if (p == 15) {
#pragma unroll
        for (int c6 = 0; c6 < 6; ++c6) P[q][c6] = 0.f;
      }
    }
    int rb = row * ED_STRIDE + part * 2;
#pragma unroll
    for (int comp = 0; comp < 6; ++comp) {
      lds[rb + comp * 8 + 0] = packbf(P[0][comp], P[1][comp]);
      lds[rb + comp * 8 + 1] = packbf(P[2][comp], P[3][comp]);
    }
  }
  __syncthreads();  // B3

  // ---- tts + ttt MFMAs (Ed fragments; lanes g>=2 hold k>=16 = pad -> zero) ----
  {
    int arow = wrow + col16;
    int gl = g & 1;
    bool gok = (g < 2);
    {
      int b5 = arow * ED_STRIDE + 40 + 4 * gl;
      u32x4 tmp;
      tmp.x = gok ? lds[b5 + 0] : 0u;
      tmp.y = gok ? lds[b5 + 1] : 0u;
      tmp.z = gok ? lds[b5 + 2] : 0u;
      tmp.w = gok ? lds[b5 + 3] : 0u;
      bf16x8 dfr = __builtin_bit_cast(bf16x8, tmp);
      hsA = MF16(dfr, ((const bf16x8*)g_btts16)[lane], hsA);
      hsB = MF16(dfr, ((const bf16x8*)g_btts16)[64 + lane], hsB);
    }
    bf16x8 btt0 = ((const bf16x8*)g_bttt16)[lane];
    bf16x8 btt1 = ((const bf16x8*)g_bttt16)[64 + lane];
#pragma unroll
    for (int k = 0; k < 5; ++k) {
      int bk = arow * ED_STRIDE + k * 8 + 4 * gl;
      u32x4 tmp;
      tmp.x = gok ? lds[bk + 0] : 0u;
      tmp.y = gok ? lds[bk + 1] : 0u;
      tmp.z = gok ? lds[bk + 2] : 0u;
      tmp.w = gok ? lds[bk + 3] : 0u;
      bf16x8 efr = __builtin_bit_cast(bf16x8, tmp);
      ht[k][0] = MF16(efr, btt0, ht[k][0]);
      ht[k][1] = MF16(efr, btt1, ht[k][1]);
    }
  }
  __syncthreads();  // B4: Ed/t dead everywhere; plane region writable

  // ---- pack planes (bf16) + htp registers ----
  uint32_t htp[5][2][2];
#pragma unroll
  for (int k = 0; k < 5; ++k)
#pragma unroll
    for (int n = 0; n < 2; ++n) {
      htp[k][n][0] = packbf(ht[k][n][0], ht[k][n][1]);
      htp[k][n][1] = packbf(ht[k][n][2], ht[k][n][3]);
    }
#pragma unroll
  for (int r = 0; r < 4; ++r) {
    int row = wrow + 4 * g + r;
    int dwb = row * 17 + (col16 >> 1);
    float pA = __shfl_xor(hsA[r], 1, 64);
    float pB = __shfl_xor(hsB[r], 1, 64);
    if (!(col16 & 1)) {
      lds[PLANE(0) + dwb]     = packbf(hsA[r], pA);
      lds[PLANE(0) + dwb + 8] = packbf(hsB[r], pB);
    }
#pragma unroll
    for (int k = 0; k < 5; ++k) {
      float qA = __shfl_xor(ht[k][0][r], 1, 64);
      float qB = __shfl_xor(ht[k][1][r], 1, 64);
      if (!(col16 & 1)) {
        lds[PLANE(1 + k) + dwb]     = packbf(ht[k][0][r], qA);
        lds[PLANE(1 + k) + dwb + 8] = packbf(ht[k][1][r], qB);
      }
    }
  }
  // (no barrier: each wave reads back only its own rows; per-wave LDS is in-order)

  // ---- tp2 GEMMs: g2 and gt_i (K=32 over hidden) ----
  f32x4 g2n[2];
  {
    int prow = wrow + col16;
    int b = PLANE(0) + prow * 17 + 4 * g;
    u32x4 tmp;
    tmp.x = lds[b]; tmp.y = lds[b + 1]; tmp.z = lds[b + 2]; tmp.w = lds[b + 3];
    bf16x8 af = __builtin_bit_cast(bf16x8, tmp);
    g2n[0] = MF16(af, ((const bf16x8*)g_bg2_16)[lane], zero4);
    g2n[1] = MF16(af, ((const bf16x8*)g_bg2_16)[64 + lane], zero4);
  }
  f32x4 gt[5][2];
#pragma unroll
  for (int i = 0; i < 5; ++i) {
    int prow = wrow + col16;
    int b = PLANE(1 + i) + prow * 17 + 4 * g;
    u32x4 tmp;
    tmp.x = lds[b]; tmp.y = lds[b + 1]; tmp.z = lds[b + 2]; tmp.w = lds[b + 3];
    bf16x8 af = __builtin_bit_cast(bf16x8, tmp);
    gt[i][0] = MF16(af, ((const bf16x8*)g_bgt16)[lane], zero4);
    gt[i][1] = MF16(af, ((const bf16x8*)g_bgt16)[64 + lane], zero4);
  }

#define HT_(k, n, r) (((r) & 1) ? bfhi(htp[k][n][(r) >> 1]) : bflo(htp[k][n][(r) >> 1]))
#define REDSTORE(K)                                                        \
  {                                                                        \
    _Pragma("unroll") for (int m = 1; m <= 8; m <<= 1)                     \
        _Pragma("unroll") for (int r = 0; r < 4; ++r)                      \
            tot[r] += __shfl_xor(tot[r], m, 64);                           \
    if (col16 == (K)) {                                                    \
      _Pragma("unroll") for (int r = 0; r < 4; ++r)                        \
          out[(size_t)(rows64 + wrow + 4 * g + r) * 5 + (K)] = tot[r];     \
    }                                                                      \
  }

  // ---- o-phase: per-k gather + immediate butterfly + store ----
  {  // k = 0
    float tot[4];
#pragma unroll
    for (int r = 0; r < 4; ++r) {
      float s = 0.f;
#pragma unroll
      for (int n = 0; n < 2; ++n) {
        float ok = g2n[n][r] * HT_(0, n, r);
        ok = fmaf(-CW1, gt[0][n][r] * HT_(2, n, r) + gt[2][n][r] * HT_(0, n, r), ok);
        ok = fmaf( CW2, gt[1][n][r] * HT_(3, n, r) + gt[3][n][r] * HT_(1, n, r), ok);
        s += ok;
      }
      tot[r] = s;
    }
    REDSTORE(0)
  }
  {  // k = 1
    float tot[4];
#pragma unroll
    for (int r = 0; r < 4; ++r) {
      float s = 0.f;
#pragma unroll
      for (int n = 0; n < 2; ++n) {
        float ok = g2n[n][r] * HT_(1, n, r);
        ok = fmaf( CW2, gt[0][n][r] * HT_(3, n, r) + gt[3][n][r] * HT_(0, n, r), ok);
        ok = fmaf( CW3, gt[1][n][r] * HT_(2, n, r) + gt[2][n][r] * HT_(1, n, r), ok);
        ok = fmaf(-CW2, gt[1][n][r] * HT_(4, n, r) + gt[4][n][r] * HT_(1, n, r), ok);
        s += ok;
      }
      tot[r] = s;
    }
    REDSTORE(1)
  }
  {  // k = 2
    float tot[4];
#pragma unroll
    for (int r = 0; r < 4; ++r) {
      float s = 0.f;
#pragma unroll
      for (int n = 0; n < 2; ++n) {
        float ok = g2n[n][r] * HT_(2, n, r);
        ok = fmaf(-CW1, gt[0][n][r] * HT_(0, n, r), ok);
        ok = fmaf( CW3, gt[1][n][r] * HT_(1, n, r), ok);
        ok = fmaf( CW1, gt[2][n][r] * HT_(2, n, r), ok);
        ok = fmaf( CW3, gt[3][n][r] * HT_(3, n, r), ok);
        ok = fmaf(-CW1, gt[4][n][r] * HT_(4, n, r), ok);
        s += ok;
      }
      tot[r] = s;
    }
    REDSTORE(2)
  }
  {  // k = 3
    float tot[4];
#pragma unroll
    for (int r = 0; r < 4; ++r) {
      float s = 0.f;
#pragma unroll
      for (int n = 0; n < 2; ++n) {
        float ok = g2n[n][r] * HT_(3, n, r);
        ok = fmaf( CW2, gt[0][n][r] * HT_(1, n, r) + gt[1][n][r] * HT_(0, n, r), ok);
        ok = fmaf( CW3, gt[2][n][r] * HT_(3, n, r) + gt[3][n][r] * HT_(2, n, r), ok);
        ok = fmaf( CW2, gt[3][n][r] * HT_(4, n, r) + gt[4][n][r] * HT_(3, n, r), ok);
        s += ok;
      }
      tot[r] = s;
    }
    REDSTORE(3)
  }
  {  // k = 4
    float tot[4];
#pragma unroll
    for (int r = 0; r < 4; ++r) {
      float s = 0.f;
#pragma unroll
      for (int n = 0; n < 2; ++n) {
        float ok = g2n[n][r] * HT_(4, n, r);
        ok = fmaf(-CW2, gt[1][n][r] * HT_(1, n, r), ok);
        ok = fmaf(-CW1, gt[2][n][r] * HT_(4, n, r) + gt[4][n][r] * HT_(2, n, r), ok);
        ok = fmaf( CW2, gt[3][n][r] * HT_(3, n, r), ok);
        s += ok;
      }
      tot[r] = s;
    }
    REDSTORE(4)
  }
}

extern "C" void kernel_launch(void* const* d_in, const int* in_sizes, int n_in,
                              void* d_out, int out_size, void* d_ws, size_t ws_size,
                              hipStream_t stream) {
  (void)n_in; (void)out_size; (void)d_ws; (void)ws_size;
  const float* scalars = (const float*)d_in[0];
  const float* tk  = (const float*)d_in[1];
  const float* tm  = (const float*)d_in[2];
  const float* tc  = (const float*)d_in[3];
  const float* tb  = (const float*)d_in[4];
  const float* tmc = (const float*)d_in[5];

  ech_prep<<<284, 256, 0, stream>>>((const float*)d_in[6], (const float*)d_in[7],
                                    (const float*)d_in[8], (const float*)d_in[9],
                                    (const float*)d_in[10], (const float*)d_in[11],
                                    (const float*)d_in[12], (const float*)d_in[13]);

  const int B = in_sizes[0] / 64;
  ech_fused<<<B / 64, 256, 0, stream>>>(scalars, tk, tm, tc, tb, tmc, (float*)d_out);
}

// Round 9
// 107.047 us; speedup vs baseline: 1.5695x; 1.3053x over previous
//
#include <hip/hip_runtime.h>
#include <math.h>
#include <stdint.h>

// ---------------------------------------------------------------------------
// EquivariantCorrectionHead, MFMA formulation v8.
// B=131072, NS=64, H=32. Block = 256 thr (4 waves), 64 batch rows/block.
// 16x16x32 fragments (f32x4 accs). launch_bounds(256,2): 128 arch-reg cap,
// spill-free. o-phase uses f32 ht registers directly (no bf16 re-rounding of
// product terms -> absmax back to ~0.1). s hi+lo split on GEMM1/stt A side.
// LDS 26KB with region reuse: s(hi/lo)+t -> Ed -> 6 bf16 planes.
// ---------------------------------------------------------------------------

#define CW1 0.23904572186687872f  // sqrt(2/35)
#define CW2 0.20701966780270626f  // sqrt(3/70)
#define CW3 0.11952286093343936f  // sqrt(1/70)

typedef float f32x4 __attribute__((ext_vector_type(4)));
typedef short bf16x8 __attribute__((ext_vector_type(8)));
typedef uint32_t u32x4 __attribute__((ext_vector_type(4)));

__device__ __forceinline__ uint32_t f2bf(float f) {  // RNE float->bf16
  uint32_t x = __float_as_uint(f);
  return (x + 0x7fffu + ((x >> 16) & 1u)) >> 16;
}
__device__ __forceinline__ uint32_t packbf(float lo, float hi) {
  return f2bf(lo) | (f2bf(hi) << 16);
}
__device__ __forceinline__ float bflo(uint32_t d) { return __uint_as_float(d << 16); }
__device__ __forceinline__ float bfhi(uint32_t d) { return __uint_as_float(d & 0xffff0000u); }
__device__ __forceinline__ float bfval(uint32_t h) { return __uint_as_float(h << 16); }

#define MF16(a, b, c) __builtin_amdgcn_mfma_f32_16x16x32_bf16((a), (b), (c), 0, 0, 0)

// B-fragment tables, 16x16x32 convention:
// lane l: g=l>>4, col=l&15 (col index = n*16 + (l&15)); dword d holds
// k = 32*c + 8*g + 2*d and k+1 (c = K-chunk where applicable).
// g_bsss16 is SYMMETRIZED upper-triangular in u (k=u): plane v needs c <= v>>5.
__device__ __align__(16) uint32_t g_bsss16[64 * 2 * 2 * 64 * 4];  // [v][n][c][l][d]
__device__ __align__(16) uint32_t g_bst16[5 * 2 * 2 * 64 * 4];    // [ct][n][c][l][d]
__device__ __align__(16) uint32_t g_btts16[2 * 64 * 4];           // [n][l][d], k=pair
__device__ __align__(16) uint32_t g_bttt16[2 * 64 * 4];           // [n][l][d], k=pair
__device__ __align__(16) uint32_t g_bg2_16[2 * 64 * 4];           // [n][l][d], k=u(32)
__device__ __align__(16) uint32_t g_bgt16[2 * 64 * 4];            // [n][l][d], k=u(32)

__device__ const int c_pu[16] = {0,0,0,0,0,1,1,1,1,2,2,2,3,3,4,0};
__device__ const int c_pv[16] = {0,1,2,3,4,1,2,3,4,2,3,4,3,4,4,0};

__global__ void ech_prep(const float* __restrict__ w1_sss, const float* __restrict__ w1_stt,
                         const float* __restrict__ w1_tst, const float* __restrict__ w1_tts,
                         const float* __restrict__ w1_ttt, const float* __restrict__ w2_stt,
                         const float* __restrict__ w2_tst, const float* __restrict__ w2_ttt) {
  const float PW1_0 = (float)(1.0 / sqrt(4121.0));
  const float PW1_2 = (float)sqrt(5.0 / 665.0);
  const float PW2_2 = (float)sqrt(5.0 / 3072.0);
  const float IS5   = (float)sqrt(0.2);

  int idx = blockIdx.x * 256 + threadIdx.x;

  if (idx < 65536) {  // g_bsss16 (symmetrized triangular)
    int d = idx & 3, l = (idx >> 2) & 63, c = (idx >> 8) & 1, n = (idx >> 9) & 1, v = idx >> 10;
    int gg = l >> 4, w = n * 16 + (l & 15);
    int u0 = 32 * c + 8 * gg + 2 * d, u1 = u0 + 1;
    float lo = 0.f, hi = 0.f;
    if (u0 < v)       lo = w1_sss[(u0 * 64 + v) * 32 + w] + w1_sss[(v * 64 + u0) * 32 + w];
    else if (u0 == v) lo = w1_sss[(u0 * 64 + v) * 32 + w];
    if (u1 < v)       hi = w1_sss[(u1 * 64 + v) * 32 + w] + w1_sss[(v * 64 + u1) * 32 + w];
    else if (u1 == v) hi = w1_sss[(u1 * 64 + v) * 32 + w];
    g_bsss16[idx] = packbf(PW1_0 * lo, PW1_0 * hi);
    return;
  }
  idx -= 65536;
  if (idx < 5120) {  // g_bst16
    int d = idx & 3, l = (idx >> 2) & 63, c = (idx >> 8) & 1, n = (idx >> 9) & 1, ct = idx >> 10;
    int gg = l >> 4, w = n * 16 + (l & 15);
    float sc = PW1_2 * IS5;
    int u0 = 32 * c + 8 * gg + 2 * d, u1 = u0 + 1;
    g_bst16[idx] = packbf(sc * (w1_stt[(u0 * 5 + ct) * 32 + w] + w1_tst[(ct * 64 + u0) * 32 + w]),
                          sc * (w1_stt[(u1 * 5 + ct) * 32 + w] + w1_tst[(ct * 64 + u1) * 32 + w]));
    return;
  }
  idx -= 5120;
  if (idx < 512) {  // g_btts16
    int d = idx & 3, l = (idx >> 2) & 63, n = idx >> 8;
    int gg = l >> 4, w = n * 16 + (l & 15);
    float sc = PW1_0 * IS5;
    float val[2];
#pragma unroll
    for (int q = 0; q < 2; ++q) {
      int p = 8 * gg + 2 * d + q;
      float x = 0.f;
      if (p < 15) {
        int u = c_pu[p], v = c_pv[p];
        x = w1_tts[(u * 5 + v) * 32 + w];
        if (u < v) x += w1_tts[(v * 5 + u) * 32 + w];
        x *= sc;
      }
      val[q] = x;
    }
    g_btts16[idx] = packbf(val[0], val[1]);
    return;
  }
  idx -= 512;
  if (idx < 512) {  // g_bttt16
    int d = idx & 3, l = (idx >> 2) & 63, n = idx >> 8;
    int gg = l >> 4, w = n * 16 + (l & 15);
    float val[2];
#pragma unroll
    for (int q = 0; q < 2; ++q) {
      int p = 8 * gg + 2 * d + q;
      float x = 0.f;
      if (p < 15) {
        int u = c_pu[p], v = c_pv[p];
        x = w1_ttt[(u * 5 + v) * 32 + w];
        if (u < v) x += w1_ttt[(v * 5 + u) * 32 + w];
        x *= PW1_2;
      }
      val[q] = x;
    }
    g_bttt16[idx] = packbf(val[0], val[1]);
    return;
  }
  idx -= 512;
  if (idx < 512) {  // g_bg2_16
    int d = idx & 3, l = (idx >> 2) & 63, n = idx >> 8;
    int gg = l >> 4, v = n * 16 + (l & 15);
    float sc = PW2_2 * IS5;
    int u0 = 8 * gg + 2 * d, u1 = u0 + 1;
    g_bg2_16[idx] = packbf(sc * (w2_stt[u0 * 32 + v] + w2_tst[v * 32 + u0]),
                           sc * (w2_stt[u1 * 32 + v] + w2_tst[v * 32 + u1]));
    return;
  }
  idx -= 512;
  if (idx < 512) {  // g_bgt16
    int d = idx & 3, l = (idx >> 2) & 63, n = idx >> 8;
    int gg = l >> 4, v = n * 16 + (l & 15);
    int u0 = 8 * gg + 2 * d, u1 = u0 + 1;
    g_bgt16[idx] = packbf(PW2_2 * w2_ttt[u0 * 32 + v], PW2_2 * w2_ttt[u1 * 32 + v]);
    return;
  }
}

// LDS (dwords), total 6528 dw = 26112 B:
//  phase1: s interleaved hi/lo [64 rows][66] @0 (4224); t f32 [64][25] @4224 (1600)
//  phase2: Ed bf16 [64 rows][49] @0 (3136; overwrites s; t stays live)
//  phase3: planes bf16 [64 rows][17] x6 @ i*1088 (6528; overwrites everything)
#define OFF_T 4224
#define ED_STRIDE 49
#define PLANE(i) ((i) * 1088)
#define LDS_DW 6528

__global__ __launch_bounds__(256, 2)
void ech_fused(const float* __restrict__ scalars,
               const float* __restrict__ tk, const float* __restrict__ tm,
               const float* __restrict__ tc, const float* __restrict__ tb,
               const float* __restrict__ tmc,
               float* __restrict__ out) {
  __shared__ uint32_t lds[LDS_DW];

  const int tid = threadIdx.x;
  const int rows64 = blockIdx.x * 64;
  const int wave = tid >> 6, lane = tid & 63;
  const int g = lane >> 4, col16 = lane & 15;
  const int wrow = wave * 16;
  const f32x4 zero4 = {0.f, 0.f, 0.f, 0.f};

  // ---- stage s: hi/lo interleaved, row stride 66 (dword 2j=hi pair, 2j+1=lo) ----
#pragma unroll
  for (int it = 0; it < 8; ++it) {
    int di = it * 256 + tid;  // 2048
    int row = di >> 5, j = di & 31;
    float f0 = scalars[(rows64 + row) * 64 + 2 * j];
    float f1 = scalars[(rows64 + row) * 64 + 2 * j + 1];
    uint32_t h0 = f2bf(f0), h1 = f2bf(f1);
    float r0 = f0 - bfval(h0), r1 = f1 - bfval(h1);
    lds[row * 66 + 2 * j]     = h0 | (h1 << 16);
    lds[row * 66 + 2 * j + 1] = f2bf(r0) | (f2bf(r1) << 16);
  }
  // ---- stage t ----
#pragma unroll
  for (int v = 0; v < 5; ++v) {
    const float* p = (v == 0 ? tk : v == 1 ? tm : v == 2 ? tc : v == 3 ? tb : tmc);
#pragma unroll
    for (int it = 0; it < 2; ++it) {
      int i = it * 256 + tid;
      if (i < 320)
        lds[OFF_T + (i / 5) * 25 + v * 5 + (i % 5)] = __float_as_uint(p[rows64 * 5 + i]);
    }
  }
  __syncthreads();  // B1

  // ---- A-fragments for s (hi, lo), K-chunks c=0,1 ----
  bf16x8 afr_hi[2], afr_lo[2];
#pragma unroll
  for (int c = 0; c < 2; ++c) {
    int base = (wrow + col16) * 66 + 32 * c + 8 * g;
    u32x4 th, tl;
    th.x = lds[base + 0]; tl.x = lds[base + 1];
    th.y = lds[base + 2]; tl.y = lds[base + 3];
    th.z = lds[base + 4]; tl.z = lds[base + 5];
    th.w = lds[base + 6]; tl.w = lds[base + 7];
    afr_hi[c] = __builtin_bit_cast(bf16x8, th);
    afr_lo[c] = __builtin_bit_cast(bf16x8, tl);
  }

  // ---- GEMM1 (sss, triangular, hi/lo A, f32 multiplier) ----
  f32x4 hsA = zero4, hsB = zero4;  // n=0, n=1
  const bf16x8* gb = (const bf16x8*)g_bsss16;
#pragma unroll 2
  for (int vd = 0; vd < 16; ++vd) {  // v<32: chunk c=0 only
    int v0 = 2 * vd, v1 = v0 + 1;
    bf16x8 b00 = gb[(v0 * 4 + 0) * 64 + lane];
    bf16x8 b01 = gb[(v0 * 4 + 2) * 64 + lane];
    bf16x8 b10 = gb[(v1 * 4 + 0) * 64 + lane];
    bf16x8 b11 = gb[(v1 * 4 + 2) * 64 + lane];
    f32x4 Z00 = zero4, Z01 = zero4, Z10 = zero4, Z11 = zero4;
    Z00 = MF16(afr_hi[0], b00, Z00); Z00 = MF16(afr_lo[0], b00, Z00);
    Z01 = MF16(afr_hi[0], b01, Z01); Z01 = MF16(afr_lo[0], b01, Z01);
    Z10 = MF16(afr_hi[0], b10, Z10); Z10 = MF16(afr_lo[0], b10, Z10);
    Z11 = MF16(afr_hi[0], b11, Z11); Z11 = MF16(afr_lo[0], b11, Z11);
#pragma unroll
    for (int r = 0; r < 4; ++r) {
      int row = wrow + 4 * g + r;
      uint32_t dh = lds[row * 66 + 2 * vd];
      uint32_t dl = lds[row * 66 + 2 * vd + 1];
      float s0 = bflo(dh) + bflo(dl);
      float s1 = bfhi(dh) + bfhi(dl);
      hsA[r] = fmaf(s0, Z00[r], hsA[r]); hsA[r] = fmaf(s1, Z10[r], hsA[r]);
      hsB[r] = fmaf(s0, Z01[r], hsB[r]); hsB[r] = fmaf(s1, Z11[r], hsB[r]);
    }
  }
#pragma unroll 2
  for (int vd = 16; vd < 32; ++vd) {  // v>=32: chunks c=0,1
    int v0 = 2 * vd, v1 = v0 + 1;
    f32x4 Z00 = zero4, Z01 = zero4, Z10 = zero4, Z11 = zero4;
#pragma unroll
    for (int c = 0; c < 2; ++c) {
      bf16x8 b00 = gb[(v0 * 4 + 0 + c) * 64 + lane];
      bf16x8 b01 = gb[(v0 * 4 + 2 + c) * 64 + lane];
      bf16x8 b10 = gb[(v1 * 4 + 0 + c) * 64 + lane];
      bf16x8 b11 = gb[(v1 * 4 + 2 + c) * 64 + lane];
      Z00 = MF16(afr_hi[c], b00, Z00); Z00 = MF16(afr_lo[c], b00, Z00);
      Z01 = MF16(afr_hi[c], b01, Z01); Z01 = MF16(afr_lo[c], b01, Z01);
      Z10 = MF16(afr_hi[c], b10, Z10); Z10 = MF16(afr_lo[c], b10, Z10);
      Z11 = MF16(afr_hi[c], b11, Z11); Z11 = MF16(afr_lo[c], b11, Z11);
    }
#pragma unroll
    for (int r = 0; r < 4; ++r) {
      int row = wrow + 4 * g + r;
      uint32_t dh = lds[row * 66 + 2 * vd];
      uint32_t dl = lds[row * 66 + 2 * vd + 1];
      float s0 = bflo(dh) + bflo(dl);
      float s1 = bfhi(dh) + bfhi(dl);
      hsA[r] = fmaf(s0, Z00[r], hsA[r]); hsA[r] = fmaf(s1, Z10[r], hsA[r]);
      hsB[r] = fmaf(s0, Z01[r], hsB[r]); hsB[r] = fmaf(s1, Z11[r], hsB[r]);
    }
  }

  // ---- stt GEMM folded into ht[k][n] ----
  f32x4 ht[5][2];
#pragma unroll
  for (int k = 0; k < 5; ++k) { ht[k][0] = zero4; ht[k][1] = zero4; }
  {
    const bf16x8* gs = (const bf16x8*)g_bst16;
#pragma unroll
    for (int ct = 0; ct < 5; ++ct) {
      f32x4 a0 = zero4, a1 = zero4;
#pragma unroll
      for (int c = 0; c < 2; ++c) {
        bf16x8 b0 = gs[(ct * 4 + 0 + c) * 64 + lane];
        bf16x8 b1 = gs[(ct * 4 + 2 + c) * 64 + lane];
        a0 = MF16(afr_hi[c], b0, a0); a0 = MF16(afr_lo[c], b0, a0);
        a1 = MF16(afr_hi[c], b1, a1); a1 = MF16(afr_lo[c], b1, a1);
      }
#pragma unroll
      for (int r = 0; r < 4; ++r) {
        int row = wrow + 4 * g + r;
        int tbi = OFF_T + row * 25 + ct * 5;
        float t0 = __uint_as_float(lds[tbi + 0]);
        float t1 = __uint_as_float(lds[tbi + 1]);
        float t2 = __uint_as_float(lds[tbi + 2]);
        float t3 = __uint_as_float(lds[tbi + 3]);
        float t4 = __uint_as_float(lds[tbi + 4]);
        ht[0][0][r] = fmaf(a0[r], t0, ht[0][0][r]); ht[0][1][r] = fmaf(a1[r], t0, ht[0][1][r]);
        ht[1][0][r] = fmaf(a0[r], t1, ht[1][0][r]); ht[1][1][r] = fmaf(a1[r], t1, ht[1][1][r]);
        ht[2][0][r] = fmaf(a0[r], t2, ht[2][0][r]); ht[2][1][r] = fmaf(a1[r], t2, ht[2][1][r]);
        ht[3][0][r] = fmaf(a0[r], t3, ht[3][0][r]); ht[3][1][r] = fmaf(a1[r], t3, ht[3][1][r]);
        ht[4][0][r] = fmaf(a0[r], t4, ht[4][0][r]); ht[4][1][r] = fmaf(a1[r], t4, ht[4][1][r]);
      }
    }
  }
  __syncthreads();  // B2: s region dead; Ed becomes writable

  // ---- E/d phase: 4 threads per row; EDP inputs read from LDS (t region) ----
  {
    int row = tid >> 2, part = tid & 3;
    int tbase = OFF_T + row * 25;
    float P[4][6];
#pragma unroll
    for (int q = 0; q < 4; ++q) {
      int p = part * 4 + q;
      int U = c_pu[p], V = c_pv[p];
      float a0 = __uint_as_float(lds[tbase + U * 5 + 0]);
      float a1 = __uint_as_float(lds[tbase + U * 5 + 1]);
      float a2 = __uint_as_float(lds[tbase + U * 5 + 2]);
      float a3 = __uint_as_float(lds[tbase + U * 5 + 3]);
      float a4 = __uint_as_float(lds[tbase + U * 5 + 4]);
      float b0 = __uint_as_float(lds[tbase + V * 5 + 0]);
      float b1 = __uint_as_float(lds[tbase + V * 5 + 1]);
      float b2 = __uint_as_float(lds[tbase + V * 5 + 2]);
      float b3 = __uint_as_float(lds[tbase + V * 5 + 3]);
      float b4 = __uint_as_float(lds[tbase + V * 5 + 4]);
      float d0 = a0 * b0, d1 = a1 * b1, d2 = a2 * b2, d3 = a3 * b3, d4 = a4 * b4;
      float s01 = a0 * b1 + a1 * b0;
      float s02 = a0 * b2 + a2 * b0;
      float s03 = a0 * b3 + a3 * b0;
      float s12 = a1 * b2 + a2 * b1;
      float s13 = a1 * b3 + a3 * b1;
      float s14 = a1 * b4 + a4 * b1;
      float s23 = a2 * b3 + a3 * b2;
      float s24 = a2 * b4 + a4 * b2;
      float s34 = a3 * b4 + a4 * b3;
      P[q][0] = -CW1 * s02 + CW2 * s13;
      P[q][1] = CW2 * s03 + CW3 * s12 - CW2 * s14;
      P[q][2] = -CW1 * d0 + CW3 * d1 + CW1 * d2 + CW3 * d3 - CW1 * d4;
      P[q][3] = CW2 * s01 + CW3 * s23 + CW2 * s34;
      P[q][4] = -CW2 * d1 - CW1 * s24 + CW2 * d3;
      P[q][5] = d0 + d1 + d2 + d3 + d4;
      if (p == 15) {
#pragma unroll
        for (int c6 = 0; c6 < 6; ++c6) P[q][c6] = 0.f;
      }
    }
    int rb = row * ED_STRIDE + part * 2;
#pragma unroll
    for (int comp = 0; comp < 6; ++comp) {
      lds[rb + comp * 8 + 0] = packbf(P[0][comp], P[1][comp]);
      lds[rb + comp * 8 + 1] = packbf(P[2][comp], P[3][comp]);
    }
  }
  __syncthreads();  // B3

  // ---- tts + ttt MFMAs (Ed fragments; lanes g>=2 hold k>=16 = pad -> zero) ----
  {
    int arow = wrow + col16;
    int gl = g & 1;
    bool gok = (g < 2);
    {
      int b5 = arow * ED_STRIDE + 40 + 4 * gl;
      u32x4 tmp;
      tmp.x = gok ? lds[b5 + 0] : 0u;
      tmp.y = gok ? lds[b5 + 1] : 0u;
      tmp.z = gok ? lds[b5 + 2] : 0u;
      tmp.w = gok ? lds[b5 + 3] : 0u;
      bf16x8 dfr = __builtin_bit_cast(bf16x8, tmp);
      hsA = MF16(dfr, ((const bf16x8*)g_btts16)[lane], hsA);
      hsB = MF16(dfr, ((const bf16x8*)g_btts16)[64 + lane], hsB);
    }
    bf16x8 btt0 = ((const bf16x8*)g_bttt16)[lane];
    bf16x8 btt1 = ((const bf16x8*)g_bttt16)[64 + lane];
#pragma unroll
    for (int k = 0; k < 5; ++k) {
      int bk = arow * ED_STRIDE + k * 8 + 4 * gl;
      u32x4 tmp;
      tmp.x = gok ? lds[bk + 0] : 0u;
      tmp.y = gok ? lds[bk + 1] : 0u;
      tmp.z = gok ? lds[bk + 2] : 0u;
      tmp.w = gok ? lds[bk + 3] : 0u;
      bf16x8 efr = __builtin_bit_cast(bf16x8, tmp);
      ht[k][0] = MF16(efr, btt0, ht[k][0]);
      ht[k][1] = MF16(efr, btt1, ht[k][1]);
    }
  }
  __syncthreads();  // B4: Ed/t dead everywhere; plane region writable

  // ---- pack planes (bf16); ht f32 registers stay LIVE for the o-phase ----
#pragma unroll
  for (int r = 0; r < 4; ++r) {
    int row = wrow + 4 * g + r;
    int dwb = row * 17 + (col16 >> 1);
    float pA = __shfl_xor(hsA[r], 1, 64);
    float pB = __shfl_xor(hsB[r], 1, 64);
    if (!(col16 & 1)) {
      lds[PLANE(0) + dwb]     = packbf(hsA[r], pA);
      lds[PLANE(0) + dwb + 8] = packbf(hsB[r], pB);
    }
#pragma unroll
    for (int k = 0; k < 5; ++k) {
      float qA = __shfl_xor(ht[k][0][r], 1, 64);
      float qB = __shfl_xor(ht[k][1][r], 1, 64);
      if (!(col16 & 1)) {
        lds[PLANE(1 + k) + dwb]     = packbf(ht[k][0][r], qA);
        lds[PLANE(1 + k) + dwb + 8] = packbf(ht[k][1][r], qB);
      }
    }
  }
  // (no barrier: each wave reads back only its own rows; per-wave LDS is in-order)

  // ---- tp2 GEMMs: g2 and gt_i (K=32 over hidden) ----
  f32x4 g2n[2];
  {
    int prow = wrow + col16;
    int b = PLANE(0) + prow * 17 + 4 * g;
    u32x4 tmp;
    tmp.x = lds[b]; tmp.y = lds[b + 1]; tmp.z = lds[b + 2]; tmp.w = lds[b + 3];
    bf16x8 af = __builtin_bit_cast(bf16x8, tmp);
    g2n[0] = MF16(af, ((const bf16x8*)g_bg2_16)[lane], zero4);
    g2n[1] = MF16(af, ((const bf16x8*)g_bg2_16)[64 + lane], zero4);
  }
  f32x4 gt[5][2];
#pragma unroll
  for (int i = 0; i < 5; ++i) {
    int prow = wrow + col16;
    int b = PLANE(1 + i) + prow * 17 + 4 * g;
    u32x4 tmp;
    tmp.x = lds[b]; tmp.y = lds[b + 1]; tmp.z = lds[b + 2]; tmp.w = lds[b + 3];
    bf16x8 af = __builtin_bit_cast(bf16x8, tmp);
    gt[i][0] = MF16(af, ((const bf16x8*)g_bgt16)[lane], zero4);
    gt[i][1] = MF16(af, ((const bf16x8*)g_bgt16)[64 + lane], zero4);
  }

#define REDSTORE(K)                                                        \
  {                                                                        \
    _Pragma("unroll") for (int m = 1; m <= 8; m <<= 1)                     \
        _Pragma("unroll") for (int r = 0; r < 4; ++r)                      \
            tot[r] += __shfl_xor(tot[r], m, 64);                           \
    if (col16 == (K)) {                                                    \
      _Pragma("unroll") for (int r = 0; r < 4; ++r)                        \
          out[(size_t)(rows64 + wrow + 4 * g + r) * 5 + (K)] = tot[r];     \
    }                                                                      \
  }

  // ---- o-phase: per-k gather (f32 ht) + immediate butterfly + store ----
  {  // k = 0
    float tot[4];
#pragma unroll
    for (int r = 0; r < 4; ++r) {
      float s = 0.f;
#pragma unroll
      for (int n = 0; n < 2; ++n) {
        float ok = g2n[n][r] * ht[0][n][r];
        ok = fmaf(-CW1, gt[0][n][r] * ht[2][n][r] + gt[2][n][r] * ht[0][n][r], ok);
        ok = fmaf( CW2, gt[1][n][r] * ht[3][n][r] + gt[3][n][r] * ht[1][n][r], ok);
        s += ok;
      }
      tot[r] = s;
    }
    REDSTORE(0)
  }
  {  // k = 1
    float tot[4];
#pragma unroll
    for (int r = 0; r < 4; ++r) {
      float s = 0.f;
#pragma unroll
      for (int n = 0; n < 2; ++n) {
        float ok = g2n[n][r] * ht[1][n][r];
        ok = fmaf( CW2, gt[0][n][r] * ht[3][n][r] + gt[3][n][r] * ht[0][n][r], ok);
        ok = fmaf( CW3, gt[1][n][r] * ht[2][n][r] + gt[2][n][r] * ht[1][n][r], ok);
        ok = fmaf(-CW2, gt[1][n][r] * ht[4][n][r] + gt[4][n][r] * ht[1][n][r], ok);
        s += ok;
      }
      tot[r] = s;
    }
    REDSTORE(1)
  }
  {  // k = 2
    float tot[4];
#pragma unroll
    for (int r = 0; r < 4; ++r) {
      float s = 0.f;
#pragma unroll
      for (int n = 0; n < 2; ++n) {
        float ok = g2n[n][r] * ht[2][n][r];
        ok = fmaf(-CW1, gt[0][n][r] * ht[0][n][r], ok);
        ok = fmaf( CW3, gt[1][n][r] * ht[1][n][r], ok);
        ok = fmaf( CW1, gt[2][n][r] * ht[2][n][r], ok);
        ok = fmaf( CW3, gt[3][n][r] * ht[3][n][r], ok);
        ok = fmaf(-CW1, gt[4][n][r] * ht[4][n][r], ok);
        s += ok;
      }
      tot[r] = s;
    }
    REDSTORE(2)
  }
  {  // k = 3
    float tot[4];
#pragma unroll
    for (int r = 0; r < 4; ++r) {
      float s = 0.f;
#pragma unroll
      for (int n = 0; n < 2; ++n) {
        float ok = g2n[n][r] * ht[3][n][r];
        ok = fmaf( CW2, gt[0][n][r] * ht[1][n][r] + gt[1][n][r] * ht[0][n][r], ok);
        ok = fmaf( CW3, gt[2][n][r] * ht[3][n][r] + gt[3][n][r] * ht[2][n][r], ok);
        ok = fmaf( CW2, gt[3][n][r] * ht[4][n][r] + gt[4][n][r] * ht[3][n][r], ok);
        s += ok;
      }
      tot[r] = s;
    }
    REDSTORE(3)
  }
  {  // k = 4
    float tot[4];
#pragma unroll
    for (int r = 0; r < 4; ++r) {
      float s = 0.f;
#pragma unroll
      for (int n = 0; n < 2; ++n) {
        float ok = g2n[n][r] * ht[4][n][r];
        ok = fmaf(-CW2, gt[1][n][r] * ht[1][n][r], ok);
        ok = fmaf(-CW1, gt[2][n][r] * ht[4][n][r] + gt[4][n][r] * ht[2][n][r], ok);
        ok = fmaf( CW2, gt[3][n][r] * ht[3][n][r], ok);
        s += ok;
      }
      tot[r] = s;
    }
    REDSTORE(4)
  }
}

extern "C" void kernel_launch(void* const* d_in, const int* in_sizes, int n_in,
                              void* d_out, int out_size, void* d_ws, size_t ws_size,
                              hipStream_t stream) {
  (void)n_in; (void)out_size; (void)d_ws; (void)ws_size;
  const float* scalars = (const float*)d_in[0];
  const float* tk  = (const float*)d_in[1];
  const float* tm  = (const float*)d_in[2];
  const float* tc  = (const float*)d_in[3];
  const float* tb  = (const float*)d_in[4];
  const float* tmc = (const float*)d_in[5];

  ech_prep<<<284, 256, 0, stream>>>((const float*)d_in[6], (const float*)d_in[7],
                                    (const float*)d_in[8], (const float*)d_in[9],
                                    (const float*)d_in[10], (const float*)d_in[11],
                                    (const float*)d_in[12], (const float*)d_in[13]);

  const int B = in_sizes[0] / 64;
  ech_fused<<<B / 64, 256, 0, stream>>>(scalars, tk, tm, tc, tb, tmc, (float*)d_out);
}